// Round 13
// baseline (260.630 us; speedup 1.0000x reference)
//
#include <hip/hip_runtime.h>
#include <hip/hip_bf16.h>
#include <stdint.h>

typedef __attribute__((ext_vector_type(4))) float floatx4;
typedef __attribute__((ext_vector_type(8))) short shortx8;

#define NTOK 2048
#define DMODEL 1024
#define NHEAD 16
#define DHEAD 64
#define BATCH 2

static __device__ __forceinline__ unsigned short f2bf(float f) {
    union { float f; unsigned int u; } v; v.f = f;
    return (unsigned short)((v.u + 0x7FFFu + ((v.u >> 16) & 1u)) >> 16);
}

static __device__ __forceinline__ floatx4 mfma16(shortx8 a, shortx8 b, floatx4 c) {
    return __builtin_amdgcn_mfma_f32_16x16x32_bf16(a, b, c, 0, 0, 0);
}

static __device__ __forceinline__ void gl_lds16(const unsigned short* g, unsigned short* l) {
    __builtin_amdgcn_global_load_lds(
        (const __attribute__((address_space(1))) unsigned int*)g,
        (__attribute__((address_space(3))) unsigned int*)l, 16, 0, 0);
}

// log2(e)/8 : exp(s/8) == exp2(C1*s)
#define C1 0.18033688f

// ---------------- merged prep: cast Q/K/V f32->bf16 + transpose W ----------------
// blocks 0..6143: cast (3 tensors x 2048 blocks). blocks 6144..9215: W transpose.
__global__ void prep_kernel(const float* __restrict__ q, const float* __restrict__ k,
                            const float* __restrict__ v,
                            const float* __restrict__ wq, const float* __restrict__ wk,
                            const float* __restrict__ wv,
                            unsigned short* __restrict__ oq, unsigned short* __restrict__ ok,
                            unsigned short* __restrict__ ov,
                            unsigned short* __restrict__ tq, unsigned short* __restrict__ tk,
                            unsigned short* __restrict__ tv) {
    __shared__ float tile[32][33];
    int b = blockIdx.x;
    if (b < 6144) {
        int part = b >> 11, blk = b & 2047;
        const float* src = part == 0 ? q : (part == 1 ? k : v);
        unsigned short* dst = part == 0 ? oq : (part == 1 ? ok : ov);
        int i = (blk * 256 + threadIdx.x) * 8;
        floatx4 a = *(const floatx4*)(src + i);
        floatx4 c = *(const floatx4*)(src + i + 4);
        union { shortx8 s; unsigned short u[8]; } o;
        o.u[0] = f2bf(a[0]); o.u[1] = f2bf(a[1]); o.u[2] = f2bf(a[2]); o.u[3] = f2bf(a[3]);
        o.u[4] = f2bf(c[0]); o.u[5] = f2bf(c[1]); o.u[6] = f2bf(c[2]); o.u[7] = f2bf(c[3]);
        *(shortx8*)(dst + i) = o.s;
    } else {
        int bb = b - 6144;            // 0..3071
        int z = bb >> 10, rem = bb & 1023;
        int bx = rem & 31, by = rem >> 5;
        const float* W = z == 0 ? wq : (z == 1 ? wk : wv);
        unsigned short* T = z == 0 ? tq : (z == 1 ? tk : tv);
        int tx = threadIdx.x & 31, ty = threadIdx.x >> 5;  // 32 x 8
#pragma unroll
        for (int j = 0; j < 4; j++)
            tile[ty + j * 8][tx] = W[(by * 32 + ty + j * 8) * DMODEL + bx * 32 + tx];
        __syncthreads();
#pragma unroll
        for (int j = 0; j < 4; j++)
            T[(bx * 32 + ty + j * 8) * DMODEL + by * 32 + tx] = f2bf(tile[tx][ty + j * 8]);
    }
}

// ---------------- projection GEMM v2: BK=64, swizzled LDS, XCD-swizzled grid ---------
// C = X @ W + b. X bf16 [4096,1024], Wt bf16 [N,K]. out: z<2 -> [B,H,N,64], z==2 -> [B,H,64,N]
__launch_bounds__(256)
__global__ void proj_gemm_kernel(const unsigned short* __restrict__ xq, const unsigned short* __restrict__ xk,
                                 const unsigned short* __restrict__ xv,
                                 const unsigned short* __restrict__ tq, const unsigned short* __restrict__ tk,
                                 const unsigned short* __restrict__ tv,
                                 const float* __restrict__ bq, const float* __restrict__ bk,
                                 const float* __restrict__ bv,
                                 unsigned short* __restrict__ qh, unsigned short* __restrict__ kh,
                                 unsigned short* __restrict__ vt) {
    // XCD swizzle: 768 blocks, 768%8==0 -> l = (bid%8)*96 + bid/8
    int bid = blockIdx.x;
    int l = (bid & 7) * 96 + (bid >> 3);
    int x = l & 7, y = (l >> 3) & 31, z = l >> 8;

    const unsigned short* X = z == 0 ? xq : (z == 1 ? xk : xv);
    const unsigned short* W = z == 0 ? tq : (z == 1 ? tk : tv);
    const float* bias = z == 0 ? bq : (z == 1 ? bk : bv);

    __shared__ unsigned short As[128 * 64];  // 16 KB
    __shared__ unsigned short Bs[128 * 64];  // 16 KB

    int t = threadIdx.x;
    int lane = t & 63, w = t >> 6;
    int wr = w >> 1, wc = w & 1;
    int r = lane & 15, g = lane >> 4;
    int m0 = y * 128, n0 = x * 128;

    floatx4 acc[4][4];
#pragma unroll
    for (int i = 0; i < 4; i++)
#pragma unroll
        for (int j = 0; j < 4; j++) acc[i][j] = (floatx4){0.f, 0.f, 0.f, 0.f};

    for (int kt = 0; kt < DMODEL; kt += 64) {
#pragma unroll
        for (int i = 0; i < 4; i++) {
            int idx = t + 256 * i;            // 0..1023
            int row = idx >> 3;               // 0..127
            int scb = (idx & 7) ^ (row & 7);  // pre-swizzled source col-block
            gl_lds16(X + (size_t)(m0 + row) * DMODEL + kt + scb * 8, As + idx * 8);
            gl_lds16(W + (size_t)(n0 + row) * DMODEL + kt + scb * 8, Bs + idx * 8);
        }
        __syncthreads();
#pragma unroll
        for (int kh = 0; kh < 2; kh++) {
            shortx8 a[4], b[4];
#pragma unroll
            for (int f = 0; f < 4; f++) {
                int arow = wr * 64 + f * 16 + r;
                a[f] = *(const shortx8*)(As + arow * 64 + ((kh * 4 + g) ^ (arow & 7)) * 8);
                int brow = wc * 64 + f * 16 + r;
                b[f] = *(const shortx8*)(Bs + brow * 64 + ((kh * 4 + g) ^ (brow & 7)) * 8);
            }
#pragma unroll
            for (int fm = 0; fm < 4; fm++)
#pragma unroll
                for (int fn = 0; fn < 4; fn++)
                    acc[fm][fn] = mfma16(a[fm], b[fn], acc[fm][fn]);
        }
        __syncthreads();
    }

    unsigned short* dstQK = (z == 0) ? qh : kh;
#pragma unroll
    for (int fm = 0; fm < 4; fm++) {
#pragma unroll
        for (int fn = 0; fn < 4; fn++) {
            int n = n0 + wc * 64 + fn * 16 + r;
            float bval = bias[n];
            int h = n >> 6, d = n & 63;
#pragma unroll
            for (int reg = 0; reg < 4; reg++) {
                int m = m0 + wr * 64 + fm * 16 + g * 4 + reg;
                int bb = m >> 11, tok = m & 2047;
                unsigned short o = f2bf(acc[fm][fn][reg] + bval);
                if (z < 2)
                    dstQK[(((size_t)(bb * NHEAD + h) * NTOK + tok) * DHEAD) + d] = o;
                else
                    vt[(((size_t)(bb * NHEAD + h) * DHEAD + d) * NTOK) + tok] = o;
            }
        }
    }
}

// ---------------- fused attention (R7 verbatim): role-alternating blocks ----------------
// role 0 (ctx): one staged sweep -> unnormalized PV + own row-sums -> ctx write.
// role 1 (attn): staged sweep A -> row-sums; staged sweep B -> normalized attn NT writes.
__launch_bounds__(256, 4)
__global__ void attn_fused_kernel(const unsigned short* __restrict__ Qh,
                                  const unsigned short* __restrict__ Kh,
                                  const unsigned short* __restrict__ Vt,
                                  float* __restrict__ ctx, float* __restrict__ attn) {
    __shared__ __align__(16) unsigned short Kst[2][4096];  // 16 KB K double-buffer
    __shared__ __align__(16) unsigned short Aux[2][4096];  // 16 KB: V dbuf (ctx) / P-flush (attn)

    int t = threadIdx.x, lane = t & 63, w = t >> 6, r = lane & 15, g = lane >> 4;

    int bid = blockIdx.y * 64 + blockIdx.x;   // grid (64, 32)
    int xcd = bid & 7;
    int j = bid >> 3;                         // 0..255
    int bh = xcd * 4 + (j & 3);               // 4 heads per XCD slice
    int rest = j >> 2;                        // 0..63
    int qb = rest >> 1;
    int role = rest & 1;

    int q0 = qb * 64 + w * 16;
    int qrow = q0 + r;
    int rs = r & 7;

    const unsigned short* Qp = Qh + ((size_t)bh * NTOK + q0) * DHEAD;
    const unsigned short* Kbase = Kh + (size_t)bh * NTOK * DHEAD;
    const unsigned short* Vbase = Vt + (size_t)bh * DHEAD * NTOK;

    shortx8 qf0 = *(const shortx8*)(Qp + r * DHEAD + g * 8);
    shortx8 qf1 = *(const shortx8*)(Qp + r * DHEAD + 32 + g * 8);

    const floatx4 zero = (floatx4){0.f, 0.f, 0.f, 0.f};

    auto STK = [&](int b, int it) {
#pragma unroll
        for (int p = 0; p < 2; ++p) {
            int row = p * 32 + (t >> 3);
            int cb = (t & 7) ^ ((t >> 3) & 7);
            gl_lds16(Kbase + ((size_t)(it * 64 + row)) * DHEAD + cb * 8,
                     Kst[b] + p * 2048 + t * 8);
        }
    };
    auto STV = [&](int b, int it) {
#pragma unroll
        for (int p = 0; p < 2; ++p) {
            int row = p * 32 + (t >> 3);
            int cb = (t & 7) ^ ((t >> 3) & 7);
            gl_lds16(Vbase + (size_t)row * NTOK + it * 64 + cb * 8,
                     Aux[b] + p * 2048 + t * 8);
        }
    };
    auto KF = [&](int b, int tq, int h) -> shortx8 {
        return *(const shortx8*)(Kst[b] + (tq * 16 + r) * 64 + 8 * (((h * 4) + g) ^ rs));
    };
    auto VF = [&](int b, int dt, int h4) -> shortx8 {
        return *(const shortx8*)(Aux[b] + (dt * 16 + r) * 64 + 8 * ((h4 + g) ^ rs));
    };

    if (role == 0) {
        // ---------------- ctx role ----------------
        floatx4 pv0 = zero, pv1 = zero, pv2 = zero, pv3 = zero;
        float sm = 0.f;
        const bool hi = (g >= 2);
        const int srcA = (r + ((g & 1) << 5)) << 2;
        const int srcB = srcA + 64;

        STK(0, 0); STV(0, 0);
        __syncthreads();
        for (int it = 0; it < 32; ++it) {
            int cur = it & 1, nxt = cur ^ 1;
            if (it < 31) { STK(nxt, it + 1); STV(nxt, it + 1); }
#pragma unroll
            for (int half = 0; half < 2; ++half) {
                unsigned int p01t0, p23t0, p01t1, p23t1;
                {
                    floatx4 sc = mfma16(KF(cur, half * 2, 0), qf0, zero);
                    sc = mfma16(KF(cur, half * 2, 1), qf1, sc);
                    float e0 = exp2f(C1 * sc[0]), e1 = exp2f(C1 * sc[1]);
                    float e2 = exp2f(C1 * sc[2]), e3 = exp2f(C1 * sc[3]);
                    sm += (e0 + e1) + (e2 + e3);
                    asm("v_cvt_pk_bf16_f32 %0, %1, %2" : "=v"(p01t0) : "v"(e0), "v"(e1));
                    asm("v_cvt_pk_bf16_f32 %0, %1, %2" : "=v"(p23t0) : "v"(e2), "v"(e3));
                }
                {
                    floatx4 sc = mfma16(KF(cur, half * 2 + 1, 0), qf0, zero);
                    sc = mfma16(KF(cur, half * 2 + 1, 1), qf1, sc);
                    float e0 = exp2f(C1 * sc[0]), e1 = exp2f(C1 * sc[1]);
                    float e2 = exp2f(C1 * sc[2]), e3 = exp2f(C1 * sc[3]);
                    sm += (e0 + e1) + (e2 + e3);
                    asm("v_cvt_pk_bf16_f32 %0, %1, %2" : "=v"(p01t1) : "v"(e0), "v"(e1));
                    asm("v_cvt_pk_bf16_f32 %0, %1, %2" : "=v"(p23t1) : "v"(e2), "v"(e3));
                }
                int b0a = __builtin_amdgcn_ds_bpermute(srcA, (int)p01t0);
                int b0b = __builtin_amdgcn_ds_bpermute(srcA, (int)p01t1);
                int b1a = __builtin_amdgcn_ds_bpermute(srcA, (int)p23t0);
                int b1b = __builtin_amdgcn_ds_bpermute(srcA, (int)p23t1);
                int b2a = __builtin_amdgcn_ds_bpermute(srcB, (int)p01t0);
                int b2b = __builtin_amdgcn_ds_bpermute(srcB, (int)p01t1);
                int b3a = __builtin_amdgcn_ds_bpermute(srcB, (int)p23t0);
                int b3b = __builtin_amdgcn_ds_bpermute(srcB, (int)p23t1);
                union { unsigned int u[4]; shortx8 s8; } pbu;
                pbu.u[0] = (unsigned)(hi ? b0b : b0a);
                pbu.u[1] = (unsigned)(hi ? b1b : b1a);
                pbu.u[2] = (unsigned)(hi ? b2b : b2a);
                pbu.u[3] = (unsigned)(hi ? b3b : b3a);
                pv0 = mfma16(VF(cur, 0, half * 4), pbu.s8, pv0);
                pv1 = mfma16(VF(cur, 1, half * 4), pbu.s8, pv1);
                pv2 = mfma16(VF(cur, 2, half * 4), pbu.s8, pv2);
                pv3 = mfma16(VF(cur, 3, half * 4), pbu.s8, pv3);
            }
            __syncthreads();
        }
        float tot = sm;
        tot += __shfl_xor(tot, 16, 64);
        tot += __shfl_xor(tot, 32, 64);
        float inv = 1.0f / tot;
        float* ctx_row =
            ctx + ((size_t)((bh >> 4) * NTOK + qrow)) * DMODEL + (bh & 15) * DHEAD + g * 4;
        *(floatx4*)(ctx_row) = pv0 * inv;
        *(floatx4*)(ctx_row + 16) = pv1 * inv;
        *(floatx4*)(ctx_row + 32) = pv2 * inv;
        *(floatx4*)(ctx_row + 48) = pv3 * inv;
    } else {
        // ---------------- attn role: sweep A (sums) ----------------
        float sm = 0.f;
        STK(0, 0);
        __syncthreads();
        for (int it = 0; it < 32; ++it) {
            int cur = it & 1, nxt = cur ^ 1;
            if (it < 31) STK(nxt, it + 1);
#pragma unroll
            for (int tq = 0; tq < 4; ++tq) {
                floatx4 sc = mfma16(KF(cur, tq, 0), qf0, zero);
                sc = mfma16(KF(cur, tq, 1), qf1, sc);
                sm += (exp2f(C1 * sc[0]) + exp2f(C1 * sc[1])) +
                      (exp2f(C1 * sc[2]) + exp2f(C1 * sc[3]));
            }
            __syncthreads();
        }
        float tot = sm;
        tot += __shfl_xor(tot, 16, 64);
        tot += __shfl_xor(tot, 32, 64);
        float nl2s = -__log2f(tot);  // exp(sc/8)/s == exp2(C1*sc + nl2s)

        // ---------------- sweep B: normalized attn writes ----------------
        float(*pw)[64] = (float(*)[64])((char*)Aux + (size_t)w * 4096);  // 4KB/wave
        float* attn_base = attn + ((size_t)bh * NTOK + q0) * NTOK;

        STK(0, 0);
        __syncthreads();
        for (int it = 0; it < 32; ++it) {
            int cur = it & 1, nxt = cur ^ 1;
            if (it < 31) STK(nxt, it + 1);
            int kk0 = it * 64;
#pragma unroll
            for (int tq = 0; tq < 4; ++tq) {
                floatx4 sc = mfma16(KF(cur, tq, 0), qf0, zero);
                sc = mfma16(KF(cur, tq, 1), qf1, sc);
                float e0 = exp2f(fmaf(C1, sc[0], nl2s));
                float e1 = exp2f(fmaf(C1, sc[1], nl2s));
                float e2 = exp2f(fmaf(C1, sc[2], nl2s));
                float e3 = exp2f(fmaf(C1, sc[3], nl2s));
                int x_ = (tq * 4 + g) ^ r;
                *(floatx4*)&pw[r][4 * x_] = (floatx4){e0, e1, e2, e3};
            }
            // coalesced NT flush: 4 stores, each 4 rows x 256B contiguous
#pragma unroll
            for (int sID = 0; sID < 4; ++sID) {
                int row = 4 * sID + g;
                floatx4 vvv = *(const floatx4*)&pw[row][4 * (r ^ row)];
                __builtin_nontemporal_store(
                    vvv, (floatx4*)(attn_base + (size_t)row * NTOK + kk0 + 4 * r));
            }
            __syncthreads();
        }
    }
}

extern "C" void kernel_launch(void* const* d_in, const int* in_sizes, int n_in,
                              void* d_out, int out_size, void* d_ws, size_t ws_size,
                              hipStream_t stream) {
    const float* query = (const float*)d_in[0];
    const float* key   = (const float*)d_in[1];
    const float* value = (const float*)d_in[2];
    const float* Wq = (const float*)d_in[3];
    const float* bq = (const float*)d_in[4];
    const float* Wk = (const float*)d_in[5];
    const float* bk = (const float*)d_in[6];
    const float* Wv = (const float*)d_in[7];
    const float* bv = (const float*)d_in[8];

    const size_t NX = (size_t)BATCH * NTOK * DMODEL;  // 4194304
    const size_t NW = (size_t)DMODEL * DMODEL;        // 1048576

    unsigned short* ws = (unsigned short*)d_ws;
    unsigned short* Xq = ws;
    unsigned short* Xk = Xq + NX;
    unsigned short* Xv = Xk + NX;
    unsigned short* Tq = Xv + NX;
    unsigned short* Tk = Tq + NW;
    unsigned short* Tv = Tk + NW;
    unsigned short* Qh = Tv + NW;
    unsigned short* Kh = Qh + NX;
    unsigned short* Vt = Kh + NX;

    float* ctx = (float*)d_out;
    float* attn = ctx + NX;

    prep_kernel<<<dim3(9216), 256, 0, stream>>>(query, key, value, Wq, Wk, Wv,
                                                Xq, Xk, Xv, Tq, Tk, Tv);
    proj_gemm_kernel<<<dim3(768), 256, 0, stream>>>(Xq, Xk, Xv, Tq, Tk, Tv,
                                                    bq, bk, bv, Qh, Kh, Vt);
    attn_fused_kernel<<<dim3(64, 32), 256, 0, stream>>>(Qh, Kh, Vt, ctx, attn);
}

// Round 14
// 248.515 us; speedup vs baseline: 1.0487x; 1.0487x over previous
//
#include <hip/hip_runtime.h>
#include <hip/hip_bf16.h>
#include <stdint.h>

typedef __attribute__((ext_vector_type(4))) float floatx4;
typedef __attribute__((ext_vector_type(8))) short shortx8;

#define NTOK 2048
#define DMODEL 1024
#define NHEAD 16
#define DHEAD 64
#define BATCH 2

static __device__ __forceinline__ unsigned short f2bf(float f) {
    union { float f; unsigned int u; } v; v.f = f;
    return (unsigned short)((v.u + 0x7FFFu + ((v.u >> 16) & 1u)) >> 16);
}

static __device__ __forceinline__ floatx4 mfma16(shortx8 a, shortx8 b, floatx4 c) {
    return __builtin_amdgcn_mfma_f32_16x16x32_bf16(a, b, c, 0, 0, 0);
}

static __device__ __forceinline__ void gl_lds16(const unsigned short* g, unsigned short* l) {
    __builtin_amdgcn_global_load_lds(
        (const __attribute__((address_space(1))) unsigned int*)g,
        (__attribute__((address_space(3))) unsigned int*)l, 16, 0, 0);
}

// log2(e)/8 : exp(s/8) == exp2(C1*s)
#define C1 0.18033688f

// ---------------- cast f32 -> bf16 for query/key/value ----------------
__global__ void cast_x_kernel(const float* __restrict__ q, const float* __restrict__ k,
                              const float* __restrict__ v,
                              unsigned short* __restrict__ oq, unsigned short* __restrict__ ok,
                              unsigned short* __restrict__ ov) {
    const float* src = blockIdx.y == 0 ? q : (blockIdx.y == 1 ? k : v);
    unsigned short* dst = blockIdx.y == 0 ? oq : (blockIdx.y == 1 ? ok : ov);
    int i = (blockIdx.x * 256 + threadIdx.x) * 8;
    floatx4 a = *(const floatx4*)(src + i);
    floatx4 b = *(const floatx4*)(src + i + 4);
    union { shortx8 s; unsigned short u[8]; } o;
    o.u[0] = f2bf(a[0]); o.u[1] = f2bf(a[1]); o.u[2] = f2bf(a[2]); o.u[3] = f2bf(a[3]);
    o.u[4] = f2bf(b[0]); o.u[5] = f2bf(b[1]); o.u[6] = f2bf(b[2]); o.u[7] = f2bf(b[3]);
    *(shortx8*)(dst + i) = o.s;
}

// ---------------- transpose + cast W [K,N] f32 -> Wt [N,K] bf16 ----------------
__global__ void transpose_w_kernel(const float* __restrict__ wq, const float* __restrict__ wk,
                                   const float* __restrict__ wv,
                                   unsigned short* __restrict__ tq, unsigned short* __restrict__ tk,
                                   unsigned short* __restrict__ tv) {
    __shared__ float tile[32][33];
    const float* W = blockIdx.z == 0 ? wq : (blockIdx.z == 1 ? wk : wv);
    unsigned short* T = blockIdx.z == 0 ? tq : (blockIdx.z == 1 ? tk : tv);
    int tx = threadIdx.x, ty = threadIdx.y;
    int bx = blockIdx.x, by = blockIdx.y;
#pragma unroll
    for (int j = 0; j < 4; j++)
        tile[ty + j * 8][tx] = W[(by * 32 + ty + j * 8) * DMODEL + bx * 32 + tx];
    __syncthreads();
#pragma unroll
    for (int j = 0; j < 4; j++)
        T[(bx * 32 + ty + j * 8) * DMODEL + by * 32 + tx] = f2bf(tile[tx][ty + j * 8]);
}

// ---------------- projection GEMM: C = X @ W + b, head-split bf16 outputs ----------------
__launch_bounds__(256)
__global__ void proj_gemm_kernel(const unsigned short* __restrict__ xq, const unsigned short* __restrict__ xk,
                                 const unsigned short* __restrict__ xv,
                                 const unsigned short* __restrict__ tq, const unsigned short* __restrict__ tk,
                                 const unsigned short* __restrict__ tv,
                                 const float* __restrict__ bq, const float* __restrict__ bk,
                                 const float* __restrict__ bv,
                                 unsigned short* __restrict__ qh, unsigned short* __restrict__ kh,
                                 unsigned short* __restrict__ vt) {
    int z = blockIdx.z;
    const unsigned short* X = z == 0 ? xq : (z == 1 ? xk : xv);
    const unsigned short* W = z == 0 ? tq : (z == 1 ? tk : tv);
    const float* bias = z == 0 ? bq : (z == 1 ? bk : bv);

    __shared__ unsigned short As[128 * 32];
    __shared__ unsigned short Bs[128 * 32];

    int t = threadIdx.x;
    int lane = t & 63, w = t >> 6;
    int wr = w >> 1, wc = w & 1;
    int r = lane & 15, g = lane >> 4;
    int m0 = blockIdx.y * 128, n0 = blockIdx.x * 128;

    floatx4 acc[4][4];
#pragma unroll
    for (int i = 0; i < 4; i++)
#pragma unroll
        for (int j = 0; j < 4; j++) acc[i][j] = (floatx4){0.f, 0.f, 0.f, 0.f};

    for (int kt = 0; kt < DMODEL; kt += 32) {
#pragma unroll
        for (int i = 0; i < 2; i++) {
            int idx = t + 256 * i;
            int row = idx >> 2, c8 = (idx & 3) * 8;
            gl_lds16(X + (size_t)(m0 + row) * DMODEL + kt + c8, As + idx * 8);
            gl_lds16(W + (size_t)(n0 + row) * DMODEL + kt + c8, Bs + idx * 8);
        }
        __syncthreads();
        shortx8 a[4], b[4];
#pragma unroll
        for (int f = 0; f < 4; f++) {
            a[f] = *(const shortx8*)(As + (wr * 64 + f * 16 + r) * 32 + g * 8);
            b[f] = *(const shortx8*)(Bs + (wc * 64 + f * 16 + r) * 32 + g * 8);
        }
#pragma unroll
        for (int fm = 0; fm < 4; fm++)
#pragma unroll
            for (int fn = 0; fn < 4; fn++)
                acc[fm][fn] = mfma16(a[fm], b[fn], acc[fm][fn]);
        __syncthreads();
    }

    unsigned short* dstQK = (z == 0) ? qh : kh;
#pragma unroll
    for (int fm = 0; fm < 4; fm++) {
#pragma unroll
        for (int fn = 0; fn < 4; fn++) {
            int n = n0 + wc * 64 + fn * 16 + r;
            float bval = bias[n];
            int h = n >> 6, d = n & 63;
#pragma unroll
            for (int reg = 0; reg < 4; reg++) {
                int m = m0 + wr * 64 + fm * 16 + g * 4 + reg;
                int bb = m >> 11, tok = m & 2047;
                unsigned short o = f2bf(acc[fm][fn][reg] + bval);
                if (z < 2)
                    dstQK[(((size_t)(bb * NHEAD + h) * NTOK + tok) * DHEAD) + d] = o;
                else
                    vt[(((size_t)(bb * NHEAD + h) * DHEAD + d) * NTOK) + tok] = o;
            }
        }
    }
}

// ---------------- fused attention: role-alternating blocks, LDS-staged K/V ----------------
// role 0 (ctx): one staged sweep -> unnormalized PV + own row-sums -> ctx write.
// role 1 (attn): staged sweep A -> row-sums; staged sweep B -> normalized attn NT writes
//   with counted s_waitcnt vmcnt(4) barriers: the 2 staging loads (issued first = oldest)
//   retire; the 4 NT stores stay in flight across the barrier (no per-iter HBM drain).
__launch_bounds__(256, 4)
__global__ void attn_fused_kernel(const unsigned short* __restrict__ Qh,
                                  const unsigned short* __restrict__ Kh,
                                  const unsigned short* __restrict__ Vt,
                                  float* __restrict__ ctx, float* __restrict__ attn) {
    __shared__ __align__(16) unsigned short Kst[2][4096];  // 16 KB K double-buffer
    __shared__ __align__(16) unsigned short Aux[2][4096];  // 16 KB: V dbuf (ctx) / P-flush (attn)

    int t = threadIdx.x, lane = t & 63, w = t >> 6, r = lane & 15, g = lane >> 4;

    // XCD-clustering remap: consecutive-dispatch blocks with same (bid&7) share a head group.
    int bid = blockIdx.y * 64 + blockIdx.x;   // grid (64, 32)
    int xcd = bid & 7;
    int j = bid >> 3;                         // 0..255
    int bh = xcd * 4 + (j & 3);               // 4 heads per XCD slice
    int rest = j >> 2;                        // 0..63
    int qb = rest >> 1;
    int role = rest & 1;

    int q0 = qb * 64 + w * 16;
    int qrow = q0 + r;
    int rs = r & 7;

    const unsigned short* Qp = Qh + ((size_t)bh * NTOK + q0) * DHEAD;
    const unsigned short* Kbase = Kh + (size_t)bh * NTOK * DHEAD;
    const unsigned short* Vbase = Vt + (size_t)bh * DHEAD * NTOK;

    shortx8 qf0 = *(const shortx8*)(Qp + r * DHEAD + g * 8);
    shortx8 qf1 = *(const shortx8*)(Qp + r * DHEAD + 32 + g * 8);

    const floatx4 zero = (floatx4){0.f, 0.f, 0.f, 0.f};

    auto STK = [&](int b, int it) {
#pragma unroll
        for (int p = 0; p < 2; ++p) {
            int row = p * 32 + (t >> 3);
            int cb = (t & 7) ^ ((t >> 3) & 7);
            gl_lds16(Kbase + ((size_t)(it * 64 + row)) * DHEAD + cb * 8,
                     Kst[b] + p * 2048 + t * 8);
        }
    };
    auto STV = [&](int b, int it) {
#pragma unroll
        for (int p = 0; p < 2; ++p) {
            int row = p * 32 + (t >> 3);
            int cb = (t & 7) ^ ((t >> 3) & 7);
            gl_lds16(Vbase + (size_t)row * NTOK + it * 64 + cb * 8,
                     Aux[b] + p * 2048 + t * 8);
        }
    };
    auto KF = [&](int b, int tq, int h) -> shortx8 {
        return *(const shortx8*)(Kst[b] + (tq * 16 + r) * 64 + 8 * (((h * 4) + g) ^ rs));
    };
    auto VF = [&](int b, int dt, int h4) -> shortx8 {
        return *(const shortx8*)(Aux[b] + (dt * 16 + r) * 64 + 8 * ((h4 + g) ^ rs));
    };

    if (role == 0) {
        // ---------------- ctx role ----------------
        floatx4 pv0 = zero, pv1 = zero, pv2 = zero, pv3 = zero;
        float sm = 0.f;
        const bool hi = (g >= 2);
        const int srcA = (r + ((g & 1) << 5)) << 2;
        const int srcB = srcA + 64;

        STK(0, 0); STV(0, 0);
        __syncthreads();
        for (int it = 0; it < 32; ++it) {
            int cur = it & 1, nxt = cur ^ 1;
            if (it < 31) { STK(nxt, it + 1); STV(nxt, it + 1); }
#pragma unroll
            for (int half = 0; half < 2; ++half) {
                unsigned int p01t0, p23t0, p01t1, p23t1;
                {
                    floatx4 sc = mfma16(KF(cur, half * 2, 0), qf0, zero);
                    sc = mfma16(KF(cur, half * 2, 1), qf1, sc);
                    float e0 = exp2f(C1 * sc[0]), e1 = exp2f(C1 * sc[1]);
                    float e2 = exp2f(C1 * sc[2]), e3 = exp2f(C1 * sc[3]);
                    sm += (e0 + e1) + (e2 + e3);
                    asm("v_cvt_pk_bf16_f32 %0, %1, %2" : "=v"(p01t0) : "v"(e0), "v"(e1));
                    asm("v_cvt_pk_bf16_f32 %0, %1, %2" : "=v"(p23t0) : "v"(e2), "v"(e3));
                }
                {
                    floatx4 sc = mfma16(KF(cur, half * 2 + 1, 0), qf0, zero);
                    sc = mfma16(KF(cur, half * 2 + 1, 1), qf1, sc);
                    float e0 = exp2f(C1 * sc[0]), e1 = exp2f(C1 * sc[1]);
                    float e2 = exp2f(C1 * sc[2]), e3 = exp2f(C1 * sc[3]);
                    sm += (e0 + e1) + (e2 + e3);
                    asm("v_cvt_pk_bf16_f32 %0, %1, %2" : "=v"(p01t1) : "v"(e0), "v"(e1));
                    asm("v_cvt_pk_bf16_f32 %0, %1, %2" : "=v"(p23t1) : "v"(e2), "v"(e3));
                }
                int b0a = __builtin_amdgcn_ds_bpermute(srcA, (int)p01t0);
                int b0b = __builtin_amdgcn_ds_bpermute(srcA, (int)p01t1);
                int b1a = __builtin_amdgcn_ds_bpermute(srcA, (int)p23t0);
                int b1b = __builtin_amdgcn_ds_bpermute(srcA, (int)p23t1);
                int b2a = __builtin_amdgcn_ds_bpermute(srcB, (int)p01t0);
                int b2b = __builtin_amdgcn_ds_bpermute(srcB, (int)p01t1);
                int b3a = __builtin_amdgcn_ds_bpermute(srcB, (int)p23t0);
                int b3b = __builtin_amdgcn_ds_bpermute(srcB, (int)p23t1);
                union { unsigned int u[4]; shortx8 s8; } pbu;
                pbu.u[0] = (unsigned)(hi ? b0b : b0a);
                pbu.u[1] = (unsigned)(hi ? b1b : b1a);
                pbu.u[2] = (unsigned)(hi ? b2b : b2a);
                pbu.u[3] = (unsigned)(hi ? b3b : b3a);
                pv0 = mfma16(VF(cur, 0, half * 4), pbu.s8, pv0);
                pv1 = mfma16(VF(cur, 1, half * 4), pbu.s8, pv1);
                pv2 = mfma16(VF(cur, 2, half * 4), pbu.s8, pv2);
                pv3 = mfma16(VF(cur, 3, half * 4), pbu.s8, pv3);
            }
            __syncthreads();
        }
        float tot = sm;
        tot += __shfl_xor(tot, 16, 64);
        tot += __shfl_xor(tot, 32, 64);
        float inv = 1.0f / tot;
        float* ctx_row =
            ctx + ((size_t)((bh >> 4) * NTOK + qrow)) * DMODEL + (bh & 15) * DHEAD + g * 4;
        *(floatx4*)(ctx_row) = pv0 * inv;
        *(floatx4*)(ctx_row + 16) = pv1 * inv;
        *(floatx4*)(ctx_row + 32) = pv2 * inv;
        *(floatx4*)(ctx_row + 48) = pv3 * inv;
    } else {
        // ---------------- attn role: sweep A (sums) ----------------
        float sm = 0.f;
        STK(0, 0);
        __syncthreads();
        for (int it = 0; it < 32; ++it) {
            int cur = it & 1, nxt = cur ^ 1;
            if (it < 31) STK(nxt, it + 1);
#pragma unroll
            for (int tq = 0; tq < 4; ++tq) {
                floatx4 sc = mfma16(KF(cur, tq, 0), qf0, zero);
                sc = mfma16(KF(cur, tq, 1), qf1, sc);
                sm += (exp2f(C1 * sc[0]) + exp2f(C1 * sc[1])) +
                      (exp2f(C1 * sc[2]) + exp2f(C1 * sc[3]));
            }
            __syncthreads();
        }
        float tot = sm;
        tot += __shfl_xor(tot, 16, 64);
        tot += __shfl_xor(tot, 32, 64);
        float nl2s = -__log2f(tot);  // exp(sc/8)/s == exp2(C1*sc + nl2s)

        // ---------------- sweep B: normalized attn writes, counted-vmcnt barriers -------
        float(*pw)[64] = (float(*)[64])((char*)Aux + (size_t)w * 4096);  // 4KB/wave
        float* attn_base = attn + ((size_t)bh * NTOK + q0) * NTOK;

        STK(0, 0);
        asm volatile("s_waitcnt vmcnt(0)" ::: "memory");
        __builtin_amdgcn_sched_barrier(0);
        __builtin_amdgcn_s_barrier();
        __builtin_amdgcn_sched_barrier(0);

        for (int it = 0; it < 32; ++it) {
            int cur = it & 1, nxt = cur ^ 1;
            // (1) staging loads FIRST: oldest vmem ops of this iteration
            if (it < 31) STK(nxt, it + 1);
            int kk0 = it * 64;
            // (2) compute P tile, stage in per-wave LDS (wave-private, DS in-order)
#pragma unroll
            for (int tq = 0; tq < 4; ++tq) {
                floatx4 sc = mfma16(KF(cur, tq, 0), qf0, zero);
                sc = mfma16(KF(cur, tq, 1), qf1, sc);
                float e0 = exp2f(fmaf(C1, sc[0], nl2s));
                float e1 = exp2f(fmaf(C1, sc[1], nl2s));
                float e2 = exp2f(fmaf(C1, sc[2], nl2s));
                float e3 = exp2f(fmaf(C1, sc[3], nl2s));
                int x_ = (tq * 4 + g) ^ r;
                *(floatx4*)&pw[r][4 * x_] = (floatx4){e0, e1, e2, e3};
            }
            // (3) coalesced NT flush: 4 stores, each 4 rows x 256B contiguous
#pragma unroll
            for (int sID = 0; sID < 4; ++sID) {
                int row = 4 * sID + g;
                floatx4 vvv = *(const floatx4*)&pw[row][4 * (r ^ row)];
                __builtin_nontemporal_store(
                    vvv, (floatx4*)(attn_base + (size_t)row * NTOK + kk0 + 4 * r));
            }
            // (4) counted wait: retire the 2 staging loads; NT stores stay in flight
            if (it < 31) {
                asm volatile("s_waitcnt vmcnt(4)" ::: "memory");
                __builtin_amdgcn_sched_barrier(0);
                __builtin_amdgcn_s_barrier();
                __builtin_amdgcn_sched_barrier(0);
            }
        }
    }
}

extern "C" void kernel_launch(void* const* d_in, const int* in_sizes, int n_in,
                              void* d_out, int out_size, void* d_ws, size_t ws_size,
                              hipStream_t stream) {
    const float* query = (const float*)d_in[0];
    const float* key   = (const float*)d_in[1];
    const float* value = (const float*)d_in[2];
    const float* Wq = (const float*)d_in[3];
    const float* bq = (const float*)d_in[4];
    const float* Wk = (const float*)d_in[5];
    const float* bk = (const float*)d_in[6];
    const float* Wv = (const float*)d_in[7];
    const float* bv = (const float*)d_in[8];

    const size_t NX = (size_t)BATCH * NTOK * DMODEL;  // 4194304
    const size_t NW = (size_t)DMODEL * DMODEL;        // 1048576

    unsigned short* ws = (unsigned short*)d_ws;
    unsigned short* Xq = ws;
    unsigned short* Xk = Xq + NX;
    unsigned short* Xv = Xk + NX;
    unsigned short* Tq = Xv + NX;
    unsigned short* Tk = Tq + NW;
    unsigned short* Tv = Tk + NW;
    unsigned short* Qh = Tv + NW;
    unsigned short* Kh = Qh + NX;
    unsigned short* Vt = Kh + NX;

    float* ctx = (float*)d_out;
    float* attn = ctx + NX;

    cast_x_kernel<<<dim3(2048, 3), 256, 0, stream>>>(query, key, value, Xq, Xk, Xv);
    transpose_w_kernel<<<dim3(32, 32, 3), dim3(32, 8), 0, stream>>>(Wq, Wk, Wv, Tq, Tk, Tv);
    proj_gemm_kernel<<<dim3(8, 32, 3), 256, 0, stream>>>(Xq, Xk, Xv, Tq, Tk, Tv,
                                                         bq, bk, bv, Qh, Kh, Vt);
    attn_fused_kernel<<<dim3(64, 32), 256, 0, stream>>>(Qh, Kh, Vt, ctx, attn);
}